// Round 1
// 263.451 us; speedup vs baseline: 1.0192x; 1.0192x over previous
//
#include <hip/hip_runtime.h>
#include <stdint.h>

#define OUT_LATENT (2048*1024)
#define SCALE 0.08838834764831845f  // 1/sqrt(128)

typedef float f32x4v __attribute__((ext_vector_type(4)));
typedef short s16x8  __attribute__((ext_vector_type(8)));

static __device__ inline unsigned short f2bf(float f) {
    union { float f; uint32_t u; } v; v.f = f;
    uint32_t u = v.u;
    return (unsigned short)((u + 0x7FFFu + ((u >> 16) & 1u)) >> 16); // RNE
}
static __device__ inline float bflo(uint32_t u) {
    union { uint32_t u; float f; } v; v.u = u << 16; return v.f;
}
static __device__ inline float bfhi(uint32_t u) {
    union { uint32_t u; float f; } v; v.u = u & 0xFFFF0000u; return v.f;
}

// async global->LDS, 16 B per lane (global_load_lds_dwordx4)
static __device__ __forceinline__ void async16(const unsigned short* g, unsigned short* l) {
    __builtin_amdgcn_global_load_lds(
        (const __attribute__((address_space(1))) void*)g,
        (__attribute__((address_space(3))) void*)l, 16, 0, 0);
}

// ---------------------------------------------------------------------------
// Kernel 2: q[d] = patch_query . wq[d,:] + bq[d].  grid 256 x 256 (1 wave/d)
__global__ __launch_bounds__(256) void k_qvec(
    const float* __restrict__ pq, const float* __restrict__ ipw,
    const float* __restrict__ ipb, float* __restrict__ qv) {
    int t = threadIdx.x, wave = t >> 6, lane = t & 63;
    int d = blockIdx.x * 4 + wave;
    const float* wrow = ipw + (size_t)d * 1024;
    float acc = 0.f;
    #pragma unroll
    for (int i = 0; i < 16; ++i) { int j = lane + i * 64; acc = fmaf(pq[j], wrow[j], acc); }
    #pragma unroll
    for (int m = 32; m >= 1; m >>= 1) acc += __shfl_xor(acc, m);
    if (lane == 0) qv[d] = acc + ipb[d];
}

// ---------------------------------------------------------------------------
// Kernel 3: qk[h][j] = SCALE * sum_d q[h*128+d] * wk[h*128+d][j]  (bf16)
//           sb[h]   = SCALE * q_h . bk_h
// grid (8 h, 16 jseg) x 256: jl = t&63 covers 64 j, dh = t>>6 splits d 4-way.
__global__ __launch_bounds__(256) void k_qk(
    const float* __restrict__ qv, const float* __restrict__ ipw,
    const float* __restrict__ ipb, unsigned short* __restrict__ qkb,
    float* __restrict__ sb) {
    __shared__ float qs[128];
    __shared__ float part[3][64];
    int h = blockIdx.x, jseg = blockIdx.y, t = threadIdx.x;
    int jl = t & 63, dh = t >> 6;
    if (t < 128) qs[t] = qv[h * 128 + t];
    __syncthreads();
    float acc = 0.f;
    const float* wbase = ipw + (size_t)(1024 + h * 128 + dh * 32) * 1024 + jseg * 64 + jl;
    #pragma unroll 8
    for (int d = 0; d < 32; ++d)
        acc = fmaf(qs[dh * 32 + d], wbase[(size_t)d * 1024], acc);
    if (dh) part[dh - 1][jl] = acc;
    __syncthreads();
    if (!dh) qkb[h * 1024 + jseg * 64 + jl] =
        f2bf((acc + part[0][jl] + part[1][jl] + part[2][jl]) * SCALE);
    if (jseg == 0 && t < 64) {
        const float* bk = ipb + 1024 + h * 128;
        float p = qs[t] * bk[t] + qs[t + 64] * bk[t + 64];
        #pragma unroll
        for (int m = 32; m >= 1; m >>= 1) p += __shfl_xor(p, m);
        if (t == 0) sb[h] = p * SCALE;
    }
}

// ---------------------------------------------------------------------------
// Kernel 4: per-patch fused gather + MFMA scores + softmax + attention mix,
// PLUS (blocks 2048..4095) the wv/out_w f32->bf16 weight conversion riding
// in the same dispatch (same DAG position: both must precede the GEMMs).
// grid 4096 x 256.  Outputs M[h][bp][j] (bf16), pv[bp], wv_b, ow_b.
__global__ __launch_bounds__(256) void k_attn_conv(
    const int* __restrict__ tok_ids, const int* __restrict__ amask,
    const float* __restrict__ emb, const unsigned short* __restrict__ qkb,
    const float* __restrict__ sb, unsigned short* __restrict__ Mout,
    float* __restrict__ pv,
    const float* __restrict__ wv_src, const float* __restrict__ ow_src,
    unsigned short* __restrict__ wv_dst, unsigned short* __restrict__ ow_dst) {
    __shared__ unsigned short tokL[16][1032];   // +8 pad: row stride 2064 B
    __shared__ float scoresP[4][16][8];         // per-wave partial score tiles
    __shared__ float attnL[16][8];
    __shared__ int allzL;

    if (blockIdx.x >= 2048) {
        // --- weight conversion path ---
        int b = blockIdx.x - 2048, t = threadIdx.x;
        const float* src; unsigned short* dst; int idx;
        if (b < 1024) { src = wv_src; dst = wv_dst; idx = b * 1024 + t * 4; }
        else          { src = ow_src; dst = ow_dst; idx = (b - 1024) * 1024 + t * 4; }
        float4 f = *(const float4*)(src + idx);
        ushort4 o; o.x = f2bf(f.x); o.y = f2bf(f.y); o.z = f2bf(f.z); o.w = f2bf(f.w);
        *(ushort4*)(dst + idx) = o;
        return;
    }

    int bp = blockIdx.x, t = threadIdx.x;
    int wave = t >> 6, lane = t & 63, lrow = lane & 15, quad = lane >> 4;

    // B-frag prefetch for scores MFMA: wave w covers k in [w*256, w*256+256).
    // B[n=lane&15][k]: head = lane&7 (cols 8..15 duplicate cols 0..7, unused).
    s16x8 bfr[8];
    {
        const unsigned short* qbase = qkb + (lane & 7) * 1024 + wave * 256 + quad * 8;
        #pragma unroll
        for (int s = 0; s < 8; ++s) bfr[s] = *(const s16x8*)(qbase + s * 32);
    }

    // gather 16 embedding rows -> LDS bf16
    {
        int row = t >> 4, c = t & 15;
        int tid = tok_ids[bp * 16 + row];
        const float* erow = emb + (size_t)tid * 1024;
        #pragma unroll
        for (int i = 0; i < 16; ++i) {
            int j4 = c + i * 16;
            float4 f = *(const float4*)(erow + j4 * 4);
            ushort4 o; o.x = f2bf(f.x); o.y = f2bf(f.y); o.z = f2bf(f.z); o.w = f2bf(f.w);
            *(ushort4*)(&tokL[row][j4 * 4]) = o;
        }
    }
    // patch-valid flag
    if (t < 16) {
        int any = (amask[bp * 16 + t] != 0);
        any |= __shfl_xor(any, 1); any |= __shfl_xor(any, 2);
        any |= __shfl_xor(any, 4); any |= __shfl_xor(any, 8);
        if (t == 0) { pv[bp] = any ? 1.f : 0.f; allzL = any ? 0 : 1; }
    }
    __syncthreads();

    // scores via MFMA: D[l][h] partial over this wave's k-range
    {
        f32x4v acc = (f32x4v){0.f, 0.f, 0.f, 0.f};
        const unsigned short* arow = &tokL[lrow][wave * 256 + quad * 8];
        #pragma unroll
        for (int s = 0; s < 8; ++s) {
            s16x8 af = *(const s16x8*)(arow + s * 32);
            acc = __builtin_amdgcn_mfma_f32_16x16x32_bf16(af, bfr[s], acc, 0, 0, 0);
        }
        if (lrow < 8) {
            #pragma unroll
            for (int r = 0; r < 4; ++r) scoresP[wave][quad * 4 + r][lrow] = acc[r];
        }
    }
    __syncthreads();

    // masked softmax over l per head (16-lane groups; t<128: hh=t>>4, ll=t&15)
    if (t < 128) {
        int hh = t >> 4, ll = t & 15;
        float s = scoresP[0][ll][hh] + scoresP[1][ll][hh]
                + scoresP[2][ll][hh] + scoresP[3][ll][hh] + sb[hh];
        bool valid = (amask[bp * 16 + ll] != 0) || (allzL && ll == 0);
        s = valid ? s : -1e30f;
        float mx = s;
        mx = fmaxf(mx, __shfl_xor(mx, 1)); mx = fmaxf(mx, __shfl_xor(mx, 2));
        mx = fmaxf(mx, __shfl_xor(mx, 4)); mx = fmaxf(mx, __shfl_xor(mx, 8));
        float e = __expf(s - mx);
        float sum = e;
        sum += __shfl_xor(sum, 1); sum += __shfl_xor(sum, 2);
        sum += __shfl_xor(sum, 4); sum += __shfl_xor(sum, 8);
        attnL[ll][hh] = e / sum;
    }
    __syncthreads();

    // mix: m[h][j] = sum_l attn[h][l] * tok[l][j]; thread owns 4 j's
    float macc[8][4];
    #pragma unroll
    for (int h = 0; h < 8; ++h)
        #pragma unroll
        for (int c = 0; c < 4; ++c) macc[h][c] = 0.f;
    #pragma unroll
    for (int ll = 0; ll < 16; ++ll) {
        uint2 tv = *(const uint2*)(&tokL[ll][t * 4]);
        float t0 = bflo(tv.x), t1 = bfhi(tv.x), t2 = bflo(tv.y), t3 = bfhi(tv.y);
        float4 a0 = *(const float4*)(&attnL[ll][0]);
        float4 a1 = *(const float4*)(&attnL[ll][4]);
        macc[0][0] = fmaf(a0.x, t0, macc[0][0]); macc[0][1] = fmaf(a0.x, t1, macc[0][1]);
        macc[0][2] = fmaf(a0.x, t2, macc[0][2]); macc[0][3] = fmaf(a0.x, t3, macc[0][3]);
        macc[1][0] = fmaf(a0.y, t0, macc[1][0]); macc[1][1] = fmaf(a0.y, t1, macc[1][1]);
        macc[1][2] = fmaf(a0.y, t2, macc[1][2]); macc[1][3] = fmaf(a0.y, t3, macc[1][3]);
        macc[2][0] = fmaf(a0.z, t0, macc[2][0]); macc[2][1] = fmaf(a0.z, t1, macc[2][1]);
        macc[2][2] = fmaf(a0.z, t2, macc[2][2]); macc[2][3] = fmaf(a0.z, t3, macc[2][3]);
        macc[3][0] = fmaf(a0.w, t0, macc[3][0]); macc[3][1] = fmaf(a0.w, t1, macc[3][1]);
        macc[3][2] = fmaf(a0.w, t2, macc[3][2]); macc[3][3] = fmaf(a0.w, t3, macc[3][3]);
        macc[4][0] = fmaf(a1.x, t0, macc[4][0]); macc[4][1] = fmaf(a1.x, t1, macc[4][1]);
        macc[4][2] = fmaf(a1.x, t2, macc[4][2]); macc[4][3] = fmaf(a1.x, t3, macc[4][3]);
        macc[5][0] = fmaf(a1.y, t0, macc[5][0]); macc[5][1] = fmaf(a1.y, t1, macc[5][1]);
        macc[5][2] = fmaf(a1.y, t2, macc[5][2]); macc[5][3] = fmaf(a1.y, t3, macc[5][3]);
        macc[6][0] = fmaf(a1.z, t0, macc[6][0]); macc[6][1] = fmaf(a1.z, t1, macc[6][1]);
        macc[6][2] = fmaf(a1.z, t2, macc[6][2]); macc[6][3] = fmaf(a1.z, t3, macc[6][3]);
        macc[7][0] = fmaf(a1.w, t0, macc[7][0]); macc[7][1] = fmaf(a1.w, t1, macc[7][1]);
        macc[7][2] = fmaf(a1.w, t2, macc[7][2]); macc[7][3] = fmaf(a1.w, t3, macc[7][3]);
    }
    #pragma unroll
    for (int h = 0; h < 8; ++h) {
        ushort4 o;
        o.x = f2bf(macc[h][0]); o.y = f2bf(macc[h][1]);
        o.z = f2bf(macc[h][2]); o.w = f2bf(macc[h][3]);
        *(ushort4*)(Mout + ((size_t)(h * 2048 + bp)) * 1024 + t * 4) = o;
    }
}

// ---------------------------------------------------------------------------
// 128x128x1024 NT bf16 MFMA mainloop — double-buffered, BK=64 staged as
// 2 x (128x32) sub-tiles (identical bank layout to the proven BK=32 form).
// T3 "minimum 2-phase": issue STAGE(next) BEFORE computing current; the
// single end-of-iter __syncthreads (vmcnt(0)+lgkmcnt(0)+barrier) lands after
// a full compute phase, so global->LDS latency hides under the MFMAs.
// A, B pre-offset to their 128-row ranges, both row-major stride 1024.
__device__ __forceinline__ void gemm128_mainloop(
    const unsigned short* __restrict__ A, const unsigned short* __restrict__ B,
    unsigned short* As, unsigned short* Bs, f32x4v acc[4][4]) {
    int t = threadIdx.x;
    int wave = t >> 6, lane = t & 63, lrow = lane & 15, quad = lane >> 4;
    int wm = wave & 1, wn = wave >> 1;
    int srow = t >> 2, sseg = (t & 3) * 8;
    size_t a0 = (size_t)srow * 1024 + sseg;
    size_t a1 = (size_t)(srow + 64) * 1024 + sseg;
    #pragma unroll
    for (int mi = 0; mi < 4; ++mi)
        #pragma unroll
        for (int ni = 0; ni < 4; ++ni) acc[mi][ni] = (f32x4v){0.f, 0.f, 0.f, 0.f};

    auto stage = [&](int step, int buf) {
        int k0 = step * 64;
        unsigned short* as = As + buf * 8192;
        unsigned short* bs = Bs + buf * 8192;
        #pragma unroll
        for (int ks = 0; ks < 2; ++ks) {
            async16(A + a0 + k0 + ks * 32, as + ks * 4096 + t * 8);
            async16(A + a1 + k0 + ks * 32, as + ks * 4096 + (256 + t) * 8);
            async16(B + a0 + k0 + ks * 32, bs + ks * 4096 + t * 8);
            async16(B + a1 + k0 + ks * 32, bs + ks * 4096 + (256 + t) * 8);
        }
    };

    stage(0, 0);
    __syncthreads();                       // drain prologue loads
    for (int s = 0; s < 16; ++s) {
        int cur = s & 1;
        if (s + 1 < 16) stage(s + 1, cur ^ 1);   // prefetch next K-tile
        const unsigned short* as = As + cur * 8192;
        const unsigned short* bs = Bs + cur * 8192;
        #pragma unroll
        for (int ks = 0; ks < 2; ++ks) {
            s16x8 af[4], bf[4];
            #pragma unroll
            for (int i = 0; i < 4; ++i) {
                af[i] = *(const s16x8*)(as + ks * 4096 + (wm * 64 + i * 16 + lrow) * 32 + quad * 8);
                bf[i] = *(const s16x8*)(bs + ks * 4096 + (wn * 64 + i * 16 + lrow) * 32 + quad * 8);
            }
            #pragma unroll
            for (int mi = 0; mi < 4; ++mi)
                #pragma unroll
                for (int ni = 0; ni < 4; ++ni)
                    acc[mi][ni] = __builtin_amdgcn_mfma_f32_16x16x32_bf16(af[mi], bf[ni], acc[mi][ni], 0, 0, 0);
        }
        __syncthreads();   // vmcnt(0): prefetch done; lgkmcnt(0)+barrier: buffers safe to swap
    }
}

// Kernel 5: ctx[bp][h*128+n] = M_h[bp,:] . wv_h[n,:] + bv   grid (16 mb, 8 h)
__global__ __launch_bounds__(256) void k_gemm_ctx(
    const unsigned short* __restrict__ M, const unsigned short* __restrict__ wv,
    const float* __restrict__ ipb, unsigned short* __restrict__ ctx) {
    __shared__ unsigned short As[2 * 8192], Bs[2 * 8192];
    int mb = blockIdx.x, h = blockIdx.y;
    f32x4v acc[4][4];
    gemm128_mainloop(M + ((size_t)h * 2048 + mb * 128) * 1024,
                     wv + (size_t)h * 128 * 1024, As, Bs, acc);
    int t = threadIdx.x, wave = t >> 6, lane = t & 63, lrow = lane & 15, quad = lane >> 4;
    int wm = wave & 1, wn = wave >> 1;
    #pragma unroll
    for (int ni = 0; ni < 4; ++ni) {
        int n_g = h * 128 + wn * 64 + ni * 16 + lrow;
        float bias = ipb[2048 + n_g];
        #pragma unroll
        for (int mi = 0; mi < 4; ++mi) {
            #pragma unroll
            for (int r = 0; r < 4; ++r) {
                int m_g = mb * 128 + wm * 64 + mi * 16 + quad * 4 + r;
                ctx[(size_t)m_g * 1024 + n_g] = f2bf(acc[mi][ni][r] + bias);
            }
        }
    }
}

// Kernel 6: out[bp][n] = (ctx[bp,:] . out_w[n,:] + out_b[n]) * pv[bp]
// grid (16 mb, 8 nb); nb==0 blocks write the pv tail.
__global__ __launch_bounds__(256) void k_gemm_out(
    const unsigned short* __restrict__ ctx, const unsigned short* __restrict__ ow,
    const float* __restrict__ outb, const float* __restrict__ pv,
    float* __restrict__ out) {
    __shared__ unsigned short As[2 * 8192], Bs[2 * 8192];
    int mb = blockIdx.x, nb = blockIdx.y;
    f32x4v acc[4][4];
    gemm128_mainloop(ctx + (size_t)mb * 128 * 1024,
                     ow + (size_t)nb * 128 * 1024, As, Bs, acc);
    int t = threadIdx.x, wave = t >> 6, lane = t & 63, lrow = lane & 15, quad = lane >> 4;
    int wm = wave & 1, wn = wave >> 1;
    #pragma unroll
    for (int ni = 0; ni < 4; ++ni) {
        int n_g = nb * 128 + wn * 64 + ni * 16 + lrow;
        float bias = outb[n_g];
        #pragma unroll
        for (int mi = 0; mi < 4; ++mi) {
            #pragma unroll
            for (int r = 0; r < 4; ++r) {
                int m_g = mb * 128 + wm * 64 + mi * 16 + quad * 4 + r;
                out[(size_t)m_g * 1024 + n_g] = (acc[mi][ni][r] + bias) * pv[m_g];
            }
        }
    }
    if (nb == 0 && t < 128) out[OUT_LATENT + mb * 128 + t] = pv[mb * 128 + t];
}

// ---------------------------------------------------------------------------
extern "C" void kernel_launch(void* const* d_in, const int* in_sizes, int n_in,
                              void* d_out, int out_size, void* d_ws, size_t ws_size,
                              hipStream_t stream) {
    const int*   tok = (const int*)d_in[0];
    const int*   msk = (const int*)d_in[1];
    const float* emb = (const float*)d_in[2];
    const float* pq  = (const float*)d_in[3];
    const float* ipw = (const float*)d_in[4];
    const float* ipb = (const float*)d_in[5];
    const float* ow  = (const float*)d_in[6];
    const float* ob  = (const float*)d_in[7];
    float* out = (float*)d_out;
    char* ws = (char*)d_ws;

    float*          q_f   = (float*)(ws + 0);                       // 4 KB
    float*          sb_f  = (float*)(ws + 4096);                    // 32 B
    float*          pv_f  = (float*)(ws + 8192);                    // 8 KB
    unsigned short* qk_b  = (unsigned short*)(ws + 16384);          // 16 KB
    unsigned short* wv_b  = (unsigned short*)(ws + 32768);          // 2 MB
    unsigned short* ow_b  = (unsigned short*)(ws + 32768 + 2097152);            // 2 MB
    unsigned short* ctx_b = (unsigned short*)(ws + 32768 + 2 * 2097152);        // 4 MB
    unsigned short* M_b   = (unsigned short*)(ws + 32768 + 2 * 2097152 + 4194304); // 32 MB

    k_qvec <<<dim3(256),   dim3(256), 0, stream>>>(pq, ipw, ipb, q_f);
    k_qk   <<<dim3(8, 16), dim3(256), 0, stream>>>(q_f, ipw, ipb, qk_b, sb_f);
    k_attn_conv<<<dim3(4096), dim3(256), 0, stream>>>(
        tok, msk, emb, qk_b, sb_f, M_b, pv_f,
        ipw + (size_t)2048 * 1024, ow, wv_b, ow_b);
    k_gemm_ctx<<<dim3(16, 8), dim3(256), 0, stream>>>(M_b, wv_b, ipb, ctx_b);
    k_gemm_out<<<dim3(16, 8), dim3(256), 0, stream>>>(ctx_b, ow_b, ob, pv_f, out);
}

// Round 2
// 249.966 us; speedup vs baseline: 1.0742x; 1.0539x over previous
//
#include <hip/hip_runtime.h>
#include <stdint.h>

#define OUT_LATENT (2048*1024)
#define SCALE 0.08838834764831845f  // 1/sqrt(128)

typedef float f32x4v __attribute__((ext_vector_type(4)));
typedef short s16x8  __attribute__((ext_vector_type(8)));

static __device__ inline unsigned short f2bf(float f) {
    union { float f; uint32_t u; } v; v.f = f;
    uint32_t u = v.u;
    return (unsigned short)((u + 0x7FFFu + ((u >> 16) & 1u)) >> 16); // RNE
}
static __device__ inline float bflo(uint32_t u) {
    union { uint32_t u; float f; } v; v.u = u << 16; return v.f;
}
static __device__ inline float bfhi(uint32_t u) {
    union { uint32_t u; float f; } v; v.u = u & 0xFFFF0000u; return v.f;
}

// async global->LDS, 16 B per lane (global_load_lds_dwordx4)
static __device__ __forceinline__ void async16(const unsigned short* g, unsigned short* l) {
    __builtin_amdgcn_global_load_lds(
        (const __attribute__((address_space(1))) void*)g,
        (__attribute__((address_space(3))) void*)l, 16, 0, 0);
}

// ---------------------------------------------------------------------------
// Kernel 2: q[d] = patch_query . wq[d,:] + bq[d].  grid 256 x 256 (1 wave/d)
__global__ __launch_bounds__(256) void k_qvec(
    const float* __restrict__ pq, const float* __restrict__ ipw,
    const float* __restrict__ ipb, float* __restrict__ qv) {
    int t = threadIdx.x, wave = t >> 6, lane = t & 63;
    int d = blockIdx.x * 4 + wave;
    const float* wrow = ipw + (size_t)d * 1024;
    float acc = 0.f;
    #pragma unroll
    for (int i = 0; i < 16; ++i) { int j = lane + i * 64; acc = fmaf(pq[j], wrow[j], acc); }
    #pragma unroll
    for (int m = 32; m >= 1; m >>= 1) acc += __shfl_xor(acc, m);
    if (lane == 0) qv[d] = acc + ipb[d];
}

// ---------------------------------------------------------------------------
// Kernel 3: qk[h][j] = SCALE * sum_d q[h*128+d] * wk[h*128+d][j]  (bf16)
//           sb[h]   = SCALE * q_h . bk_h
// grid (8 h, 16 jseg) x 256: jl = t&63 covers 64 j, dh = t>>6 splits d 4-way.
__global__ __launch_bounds__(256) void k_qk(
    const float* __restrict__ qv, const float* __restrict__ ipw,
    const float* __restrict__ ipb, unsigned short* __restrict__ qkb,
    float* __restrict__ sb) {
    __shared__ float qs[128];
    __shared__ float part[3][64];
    int h = blockIdx.x, jseg = blockIdx.y, t = threadIdx.x;
    int jl = t & 63, dh = t >> 6;
    if (t < 128) qs[t] = qv[h * 128 + t];
    __syncthreads();
    float acc = 0.f;
    const float* wbase = ipw + (size_t)(1024 + h * 128 + dh * 32) * 1024 + jseg * 64 + jl;
    #pragma unroll 8
    for (int d = 0; d < 32; ++d)
        acc = fmaf(qs[dh * 32 + d], wbase[(size_t)d * 1024], acc);
    if (dh) part[dh - 1][jl] = acc;
    __syncthreads();
    if (!dh) qkb[h * 1024 + jseg * 64 + jl] =
        f2bf((acc + part[0][jl] + part[1][jl] + part[2][jl]) * SCALE);
    if (jseg == 0 && t < 64) {
        const float* bk = ipb + 1024 + h * 128;
        float p = qs[t] * bk[t] + qs[t + 64] * bk[t + 64];
        #pragma unroll
        for (int m = 32; m >= 1; m >>= 1) p += __shfl_xor(p, m);
        if (t == 0) sb[h] = p * SCALE;
    }
}

// ---------------------------------------------------------------------------
// Kernel 4: per-patch fused gather + MFMA scores + softmax + attention mix,
// PLUS (blocks 2048..4095) the wv/out_w f32->bf16 weight conversion riding
// in the same dispatch (same DAG position: both must precede the GEMMs).
// grid 4096 x 256.  Outputs M[h][bp][j] (bf16), pv[bp], wv_b, ow_b.
__global__ __launch_bounds__(256) void k_attn_conv(
    const int* __restrict__ tok_ids, const int* __restrict__ amask,
    const float* __restrict__ emb, const unsigned short* __restrict__ qkb,
    const float* __restrict__ sb, unsigned short* __restrict__ Mout,
    float* __restrict__ pv,
    const float* __restrict__ wv_src, const float* __restrict__ ow_src,
    unsigned short* __restrict__ wv_dst, unsigned short* __restrict__ ow_dst) {
    __shared__ unsigned short tokL[16][1032];   // +8 pad: row stride 2064 B
    __shared__ float scoresP[4][16][8];         // per-wave partial score tiles
    __shared__ float attnL[16][8];
    __shared__ int allzL;

    if (blockIdx.x >= 2048) {
        // --- weight conversion path ---
        int b = blockIdx.x - 2048, t = threadIdx.x;
        const float* src; unsigned short* dst; int idx;
        if (b < 1024) { src = wv_src; dst = wv_dst; idx = b * 1024 + t * 4; }
        else          { src = ow_src; dst = ow_dst; idx = (b - 1024) * 1024 + t * 4; }
        float4 f = *(const float4*)(src + idx);
        ushort4 o; o.x = f2bf(f.x); o.y = f2bf(f.y); o.z = f2bf(f.z); o.w = f2bf(f.w);
        *(ushort4*)(dst + idx) = o;
        return;
    }

    int bp = blockIdx.x, t = threadIdx.x;
    int wave = t >> 6, lane = t & 63, lrow = lane & 15, quad = lane >> 4;

    // B-frag prefetch for scores MFMA: wave w covers k in [w*256, w*256+256).
    // B[n=lane&15][k]: head = lane&7 (cols 8..15 duplicate cols 0..7, unused).
    s16x8 bfr[8];
    {
        const unsigned short* qbase = qkb + (lane & 7) * 1024 + wave * 256 + quad * 8;
        #pragma unroll
        for (int s = 0; s < 8; ++s) bfr[s] = *(const s16x8*)(qbase + s * 32);
    }

    // gather 16 embedding rows -> LDS bf16
    {
        int row = t >> 4, c = t & 15;
        int tid = tok_ids[bp * 16 + row];
        const float* erow = emb + (size_t)tid * 1024;
        #pragma unroll
        for (int i = 0; i < 16; ++i) {
            int j4 = c + i * 16;
            float4 f = *(const float4*)(erow + j4 * 4);
            ushort4 o; o.x = f2bf(f.x); o.y = f2bf(f.y); o.z = f2bf(f.z); o.w = f2bf(f.w);
            *(ushort4*)(&tokL[row][j4 * 4]) = o;
        }
    }
    // patch-valid flag
    if (t < 16) {
        int any = (amask[bp * 16 + t] != 0);
        any |= __shfl_xor(any, 1); any |= __shfl_xor(any, 2);
        any |= __shfl_xor(any, 4); any |= __shfl_xor(any, 8);
        if (t == 0) { pv[bp] = any ? 1.f : 0.f; allzL = any ? 0 : 1; }
    }
    __syncthreads();

    // scores via MFMA: D[l][h] partial over this wave's k-range
    {
        f32x4v acc = (f32x4v){0.f, 0.f, 0.f, 0.f};
        const unsigned short* arow = &tokL[lrow][wave * 256 + quad * 8];
        #pragma unroll
        for (int s = 0; s < 8; ++s) {
            s16x8 af = *(const s16x8*)(arow + s * 32);
            acc = __builtin_amdgcn_mfma_f32_16x16x32_bf16(af, bfr[s], acc, 0, 0, 0);
        }
        if (lrow < 8) {
            #pragma unroll
            for (int r = 0; r < 4; ++r) scoresP[wave][quad * 4 + r][lrow] = acc[r];
        }
    }
    __syncthreads();

    // masked softmax over l per head (16-lane groups; t<128: hh=t>>4, ll=t&15)
    if (t < 128) {
        int hh = t >> 4, ll = t & 15;
        float s = scoresP[0][ll][hh] + scoresP[1][ll][hh]
                + scoresP[2][ll][hh] + scoresP[3][ll][hh] + sb[hh];
        bool valid = (amask[bp * 16 + ll] != 0) || (allzL && ll == 0);
        s = valid ? s : -1e30f;
        float mx = s;
        mx = fmaxf(mx, __shfl_xor(mx, 1)); mx = fmaxf(mx, __shfl_xor(mx, 2));
        mx = fmaxf(mx, __shfl_xor(mx, 4)); mx = fmaxf(mx, __shfl_xor(mx, 8));
        float e = __expf(s - mx);
        float sum = e;
        sum += __shfl_xor(sum, 1); sum += __shfl_xor(sum, 2);
        sum += __shfl_xor(sum, 4); sum += __shfl_xor(sum, 8);
        attnL[ll][hh] = e / sum;
    }
    __syncthreads();

    // mix: m[h][j] = sum_l attn[h][l] * tok[l][j]; thread owns 4 j's
    float macc[8][4];
    #pragma unroll
    for (int h = 0; h < 8; ++h)
        #pragma unroll
        for (int c = 0; c < 4; ++c) macc[h][c] = 0.f;
    #pragma unroll
    for (int ll = 0; ll < 16; ++ll) {
        uint2 tv = *(const uint2*)(&tokL[ll][t * 4]);
        float t0 = bflo(tv.x), t1 = bfhi(tv.x), t2 = bflo(tv.y), t3 = bfhi(tv.y);
        float4 a0 = *(const float4*)(&attnL[ll][0]);
        float4 a1 = *(const float4*)(&attnL[ll][4]);
        macc[0][0] = fmaf(a0.x, t0, macc[0][0]); macc[0][1] = fmaf(a0.x, t1, macc[0][1]);
        macc[0][2] = fmaf(a0.x, t2, macc[0][2]); macc[0][3] = fmaf(a0.x, t3, macc[0][3]);
        macc[1][0] = fmaf(a0.y, t0, macc[1][0]); macc[1][1] = fmaf(a0.y, t1, macc[1][1]);
        macc[1][2] = fmaf(a0.y, t2, macc[1][2]); macc[1][3] = fmaf(a0.y, t3, macc[1][3]);
        macc[2][0] = fmaf(a0.z, t0, macc[2][0]); macc[2][1] = fmaf(a0.z, t1, macc[2][1]);
        macc[2][2] = fmaf(a0.z, t2, macc[2][2]); macc[2][3] = fmaf(a0.z, t3, macc[2][3]);
        macc[3][0] = fmaf(a0.w, t0, macc[3][0]); macc[3][1] = fmaf(a0.w, t1, macc[3][1]);
        macc[3][2] = fmaf(a0.w, t2, macc[3][2]); macc[3][3] = fmaf(a0.w, t3, macc[3][3]);
        macc[4][0] = fmaf(a1.x, t0, macc[4][0]); macc[4][1] = fmaf(a1.x, t1, macc[4][1]);
        macc[4][2] = fmaf(a1.x, t2, macc[4][2]); macc[4][3] = fmaf(a1.x, t3, macc[4][3]);
        macc[5][0] = fmaf(a1.y, t0, macc[5][0]); macc[5][1] = fmaf(a1.y, t1, macc[5][1]);
        macc[5][2] = fmaf(a1.y, t2, macc[5][2]); macc[5][3] = fmaf(a1.y, t3, macc[5][3]);
        macc[6][0] = fmaf(a1.z, t0, macc[6][0]); macc[6][1] = fmaf(a1.z, t1, macc[6][1]);
        macc[6][2] = fmaf(a1.z, t2, macc[6][2]); macc[6][3] = fmaf(a1.z, t3, macc[6][3]);
        macc[7][0] = fmaf(a1.w, t0, macc[7][0]); macc[7][1] = fmaf(a1.w, t1, macc[7][1]);
        macc[7][2] = fmaf(a1.w, t2, macc[7][2]); macc[7][3] = fmaf(a1.w, t3, macc[7][3]);
    }
    #pragma unroll
    for (int h = 0; h < 8; ++h) {
        ushort4 o;
        o.x = f2bf(macc[h][0]); o.y = f2bf(macc[h][1]);
        o.z = f2bf(macc[h][2]); o.w = f2bf(macc[h][3]);
        *(ushort4*)(Mout + ((size_t)(h * 2048 + bp)) * 1024 + t * 4) = o;
    }
}

// ---------------------------------------------------------------------------
// 64x64x1024 NT bf16 MFMA mainloop — double-buffered, BK=64 staged as
// 2 x (64x32) sub-tiles (byte-identical bank layout to the proven m97 form).
// Tile shrunk 128->64 so the grid is 512 blocks = 2 blocks/CU on all 256 CUs:
// while one block sits in its end-of-step barrier drain (vmcnt(0)), the
// co-resident block's waves issue — TLP hides the global->LDS latency that
// the 1-deep prefetch alone cannot (compute/step ~200cyc << ~900cyc HBM).
// A, B pre-offset to their 64-row ranges, both row-major stride 1024.
__device__ __forceinline__ void gemm64_mainloop(
    const unsigned short* __restrict__ A, const unsigned short* __restrict__ B,
    unsigned short* As, unsigned short* Bs, f32x4v acc[2][2]) {
    int t = threadIdx.x;
    int wave = t >> 6, lane = t & 63, lrow = lane & 15, quad = lane >> 4;
    int wm = wave & 1, wn = wave >> 1;
    size_t g0 = (size_t)(t >> 2) * 1024 + (t & 3) * 8;   // row t/4, col8 t%4
    #pragma unroll
    for (int mi = 0; mi < 2; ++mi)
        #pragma unroll
        for (int ni = 0; ni < 2; ++ni) acc[mi][ni] = (f32x4v){0.f, 0.f, 0.f, 0.f};

    auto stage = [&](int step, int buf) {
        int k0 = step * 64;
        unsigned short* as = As + buf * 4096;
        unsigned short* bs = Bs + buf * 4096;
        async16(A + g0 + k0,      as + t * 8);           // A k-subtile 0
        async16(A + g0 + k0 + 32, as + 2048 + t * 8);    // A k-subtile 1
        async16(B + g0 + k0,      bs + t * 8);           // B k-subtile 0
        async16(B + g0 + k0 + 32, bs + 2048 + t * 8);    // B k-subtile 1
    };

    stage(0, 0);
    __syncthreads();                       // drain prologue loads
    for (int s = 0; s < 16; ++s) {
        int cur = s & 1;
        if (s + 1 < 16) stage(s + 1, cur ^ 1);   // prefetch next K-tile
        const unsigned short* as = As + cur * 4096;
        const unsigned short* bs = Bs + cur * 4096;
        #pragma unroll
        for (int ks = 0; ks < 2; ++ks) {
            s16x8 af[2], bf[2];
            #pragma unroll
            for (int i = 0; i < 2; ++i) {
                af[i] = *(const s16x8*)(as + ks * 2048 + (wm * 32 + i * 16 + lrow) * 32 + quad * 8);
                bf[i] = *(const s16x8*)(bs + ks * 2048 + (wn * 32 + i * 16 + lrow) * 32 + quad * 8);
            }
            #pragma unroll
            for (int mi = 0; mi < 2; ++mi)
                #pragma unroll
                for (int ni = 0; ni < 2; ++ni)
                    acc[mi][ni] = __builtin_amdgcn_mfma_f32_16x16x32_bf16(af[mi], bf[ni], acc[mi][ni], 0, 0, 0);
        }
        __syncthreads();   // vmcnt(0): prefetch done; buffers safe to swap
    }
}

// Kernel 5: ctx[bp][n] = M_h[bp,:] . wv[n,:] + bv[n], h = n>>7.
// grid (32 mb, 16 nb): 64-row M block x 64-col n block (nb*64 spans one head).
__global__ __launch_bounds__(256) void k_gemm_ctx(
    const unsigned short* __restrict__ M, const unsigned short* __restrict__ wv,
    const float* __restrict__ ipb, unsigned short* __restrict__ ctx) {
    __shared__ unsigned short As[2 * 4096], Bs[2 * 4096];
    int mb = blockIdx.x, nb = blockIdx.y, h = nb >> 1;
    f32x4v acc[2][2];
    gemm64_mainloop(M + ((size_t)h * 2048 + mb * 64) * 1024,
                    wv + (size_t)nb * 64 * 1024, As, Bs, acc);
    int t = threadIdx.x, wave = t >> 6, lane = t & 63, lrow = lane & 15, quad = lane >> 4;
    int wm = wave & 1, wn = wave >> 1;
    #pragma unroll
    for (int ni = 0; ni < 2; ++ni) {
        int n_g = nb * 64 + wn * 32 + ni * 16 + lrow;
        float bias = ipb[2048 + n_g];
        #pragma unroll
        for (int mi = 0; mi < 2; ++mi) {
            #pragma unroll
            for (int r = 0; r < 4; ++r) {
                int m_g = mb * 64 + wm * 32 + mi * 16 + quad * 4 + r;
                ctx[(size_t)m_g * 1024 + n_g] = f2bf(acc[mi][ni][r] + bias);
            }
        }
    }
}

// Kernel 6: out[bp][n] = (ctx[bp,:] . out_w[n,:] + out_b[n]) * pv[bp]
// grid (32 mb, 16 nb); nb==0 blocks write the pv tail.
__global__ __launch_bounds__(256) void k_gemm_out(
    const unsigned short* __restrict__ ctx, const unsigned short* __restrict__ ow,
    const float* __restrict__ outb, const float* __restrict__ pv,
    float* __restrict__ out) {
    __shared__ unsigned short As[2 * 4096], Bs[2 * 4096];
    int mb = blockIdx.x, nb = blockIdx.y;
    f32x4v acc[2][2];
    gemm64_mainloop(ctx + (size_t)mb * 64 * 1024,
                    ow + (size_t)nb * 64 * 1024, As, Bs, acc);
    int t = threadIdx.x, wave = t >> 6, lane = t & 63, lrow = lane & 15, quad = lane >> 4;
    int wm = wave & 1, wn = wave >> 1;
    #pragma unroll
    for (int ni = 0; ni < 2; ++ni) {
        int n_g = nb * 64 + wn * 32 + ni * 16 + lrow;
        float bias = outb[n_g];
        #pragma unroll
        for (int mi = 0; mi < 2; ++mi) {
            #pragma unroll
            for (int r = 0; r < 4; ++r) {
                int m_g = mb * 64 + wm * 32 + mi * 16 + quad * 4 + r;
                out[(size_t)m_g * 1024 + n_g] = (acc[mi][ni][r] + bias) * pv[m_g];
            }
        }
    }
    if (nb == 0 && t < 64) out[OUT_LATENT + mb * 64 + t] = pv[mb * 64 + t];
}

// ---------------------------------------------------------------------------
extern "C" void kernel_launch(void* const* d_in, const int* in_sizes, int n_in,
                              void* d_out, int out_size, void* d_ws, size_t ws_size,
                              hipStream_t stream) {
    const int*   tok = (const int*)d_in[0];
    const int*   msk = (const int*)d_in[1];
    const float* emb = (const float*)d_in[2];
    const float* pq  = (const float*)d_in[3];
    const float* ipw = (const float*)d_in[4];
    const float* ipb = (const float*)d_in[5];
    const float* ow  = (const float*)d_in[6];
    const float* ob  = (const float*)d_in[7];
    float* out = (float*)d_out;
    char* ws = (char*)d_ws;

    float*          q_f   = (float*)(ws + 0);                       // 4 KB
    float*          sb_f  = (float*)(ws + 4096);                    // 32 B
    float*          pv_f  = (float*)(ws + 8192);                    // 8 KB
    unsigned short* qk_b  = (unsigned short*)(ws + 16384);          // 16 KB
    unsigned short* wv_b  = (unsigned short*)(ws + 32768);          // 2 MB
    unsigned short* ow_b  = (unsigned short*)(ws + 32768 + 2097152);            // 2 MB
    unsigned short* ctx_b = (unsigned short*)(ws + 32768 + 2 * 2097152);        // 4 MB
    unsigned short* M_b   = (unsigned short*)(ws + 32768 + 2 * 2097152 + 4194304); // 32 MB

    k_qvec <<<dim3(256),   dim3(256), 0, stream>>>(pq, ipw, ipb, q_f);
    k_qk   <<<dim3(8, 16), dim3(256), 0, stream>>>(q_f, ipw, ipb, qk_b, sb_f);
    k_attn_conv<<<dim3(4096), dim3(256), 0, stream>>>(
        tok, msk, emb, qk_b, sb_f, M_b, pv_f,
        ipw + (size_t)2048 * 1024, ow, wv_b, ow_b);
    k_gemm_ctx<<<dim3(32, 16), dim3(256), 0, stream>>>(M_b, wv_b, ipb, ctx_b);
    k_gemm_out<<<dim3(32, 16), dim3(256), 0, stream>>>(ctx_b, ow_b, ob, pv_f, out);
}

// Round 5
// 247.865 us; speedup vs baseline: 1.0833x; 1.0085x over previous
//
#include <hip/hip_runtime.h>
#include <stdint.h>

#define OUT_LATENT (2048*1024)
#define SCALE 0.08838834764831845f  // 1/sqrt(128)

typedef float f32x4v __attribute__((ext_vector_type(4)));
typedef short s16x8  __attribute__((ext_vector_type(8)));

static __device__ inline unsigned short f2bf(float f) {
    union { float f; uint32_t u; } v; v.f = f;
    uint32_t u = v.u;
    return (unsigned short)((u + 0x7FFFu + ((u >> 16) & 1u)) >> 16); // RNE
}
static __device__ inline float bflo(uint32_t u) {
    union { uint32_t u; float f; } v; v.u = u << 16; return v.f;
}
static __device__ inline float bfhi(uint32_t u) {
    union { uint32_t u; float f; } v; v.u = u & 0xFFFF0000u; return v.f;
}

// async global->LDS, 16 B per lane (global_load_lds_dwordx4)
static __device__ __forceinline__ void async16(const unsigned short* g, unsigned short* l) {
    __builtin_amdgcn_global_load_lds(
        (const __attribute__((address_space(1))) void*)g,
        (__attribute__((address_space(3))) void*)l, 16, 0, 0);
}

// ---------------------------------------------------------------------------
// Kernel 2: q[d] = patch_query . wq[d,:] + bq[d].  grid 256 x 256 (1 wave/d)
__global__ __launch_bounds__(256) void k_qvec(
    const float* __restrict__ pq, const float* __restrict__ ipw,
    const float* __restrict__ ipb, float* __restrict__ qv) {
    int t = threadIdx.x, wave = t >> 6, lane = t & 63;
    int d = blockIdx.x * 4 + wave;
    const float* wrow = ipw + (size_t)d * 1024;
    float acc = 0.f;
    #pragma unroll
    for (int i = 0; i < 16; ++i) { int j = lane + i * 64; acc = fmaf(pq[j], wrow[j], acc); }
    #pragma unroll
    for (int m = 32; m >= 1; m >>= 1) acc += __shfl_xor(acc, m);
    if (lane == 0) qv[d] = acc + ipb[d];
}

// ---------------------------------------------------------------------------
// Kernel 3: qk[h][j] = SCALE * sum_d q[h*128+d] * wk[h*128+d][j]  (bf16)
//           sb[h]   = SCALE * q_h . bk_h
// grid (8 h, 16 jseg) x 256: jl = t&63 covers 64 j, dh = t>>6 splits d 4-way.
__global__ __launch_bounds__(256) void k_qk(
    const float* __restrict__ qv, const float* __restrict__ ipw,
    const float* __restrict__ ipb, unsigned short* __restrict__ qkb,
    float* __restrict__ sb) {
    __shared__ float qs[128];
    __shared__ float part[3][64];
    int h = blockIdx.x, jseg = blockIdx.y, t = threadIdx.x;
    int jl = t & 63, dh = t >> 6;
    if (t < 128) qs[t] = qv[h * 128 + t];
    __syncthreads();
    float acc = 0.f;
    const float* wbase = ipw + (size_t)(1024 + h * 128 + dh * 32) * 1024 + jseg * 64 + jl;
    #pragma unroll 8
    for (int d = 0; d < 32; ++d)
        acc = fmaf(qs[dh * 32 + d], wbase[(size_t)d * 1024], acc);
    if (dh) part[dh - 1][jl] = acc;
    __syncthreads();
    if (!dh) qkb[h * 1024 + jseg * 64 + jl] =
        f2bf((acc + part[0][jl] + part[1][jl] + part[2][jl]) * SCALE);
    if (jseg == 0 && t < 64) {
        const float* bk = ipb + 1024 + h * 128;
        float p = qs[t] * bk[t] + qs[t + 64] * bk[t + 64];
        #pragma unroll
        for (int m = 32; m >= 1; m >>= 1) p += __shfl_xor(p, m);
        if (t == 0) sb[h] = p * SCALE;
    }
}

// ---------------------------------------------------------------------------
// Kernel 4: per-patch fused gather + MFMA scores + softmax + attention mix,
// PLUS (blocks 2048..4095) the wv/out_w f32->bf16 weight conversion riding
// in the same dispatch (same DAG position: both must precede the GEMMs).
// grid 4096 x 256.  Outputs M[h][bp][j] (bf16), pv[bp], wv_b, ow_b.
__global__ __launch_bounds__(256) void k_attn_conv(
    const int* __restrict__ tok_ids, const int* __restrict__ amask,
    const float* __restrict__ emb, const unsigned short* __restrict__ qkb,
    const float* __restrict__ sb, unsigned short* __restrict__ Mout,
    float* __restrict__ pv,
    const float* __restrict__ wv_src, const float* __restrict__ ow_src,
    unsigned short* __restrict__ wv_dst, unsigned short* __restrict__ ow_dst) {
    __shared__ unsigned short tokL[16][1032];   // +8 pad: row stride 2064 B
    __shared__ float scoresP[4][16][8];         // per-wave partial score tiles
    __shared__ float attnL[16][8];
    __shared__ int allzL;

    if (blockIdx.x >= 2048) {
        // --- weight conversion path ---
        int b = blockIdx.x - 2048, t = threadIdx.x;
        const float* src; unsigned short* dst; int idx;
        if (b < 1024) { src = wv_src; dst = wv_dst; idx = b * 1024 + t * 4; }
        else          { src = ow_src; dst = ow_dst; idx = (b - 1024) * 1024 + t * 4; }
        float4 f = *(const float4*)(src + idx);
        ushort4 o; o.x = f2bf(f.x); o.y = f2bf(f.y); o.z = f2bf(f.z); o.w = f2bf(f.w);
        *(ushort4*)(dst + idx) = o;
        return;
    }

    int bp = blockIdx.x, t = threadIdx.x;
    int wave = t >> 6, lane = t & 63, lrow = lane & 15, quad = lane >> 4;

    // B-frag prefetch for scores MFMA: wave w covers k in [w*256, w*256+256).
    // B[n=lane&15][k]: head = lane&7 (cols 8..15 duplicate cols 0..7, unused).
    s16x8 bfr[8];
    {
        const unsigned short* qbase = qkb + (lane & 7) * 1024 + wave * 256 + quad * 8;
        #pragma unroll
        for (int s = 0; s < 8; ++s) bfr[s] = *(const s16x8*)(qbase + s * 32);
    }

    // gather 16 embedding rows -> LDS bf16
    {
        int row = t >> 4, c = t & 15;
        int tid = tok_ids[bp * 16 + row];
        const float* erow = emb + (size_t)tid * 1024;
        #pragma unroll
        for (int i = 0; i < 16; ++i) {
            int j4 = c + i * 16;
            float4 f = *(const float4*)(erow + j4 * 4);
            ushort4 o; o.x = f2bf(f.x); o.y = f2bf(f.y); o.z = f2bf(f.z); o.w = f2bf(f.w);
            *(ushort4*)(&tokL[row][j4 * 4]) = o;
        }
    }
    // patch-valid flag
    if (t < 16) {
        int any = (amask[bp * 16 + t] != 0);
        any |= __shfl_xor(any, 1); any |= __shfl_xor(any, 2);
        any |= __shfl_xor(any, 4); any |= __shfl_xor(any, 8);
        if (t == 0) { pv[bp] = any ? 1.f : 0.f; allzL = any ? 0 : 1; }
    }
    __syncthreads();

    // scores via MFMA: D[l][h] partial over this wave's k-range
    {
        f32x4v acc = (f32x4v){0.f, 0.f, 0.f, 0.f};
        const unsigned short* arow = &tokL[lrow][wave * 256 + quad * 8];
        #pragma unroll
        for (int s = 0; s < 8; ++s) {
            s16x8 af = *(const s16x8*)(arow + s * 32);
            acc = __builtin_amdgcn_mfma_f32_16x16x32_bf16(af, bfr[s], acc, 0, 0, 0);
        }
        if (lrow < 8) {
            #pragma unroll
            for (int r = 0; r < 4; ++r) scoresP[wave][quad * 4 + r][lrow] = acc[r];
        }
    }
    __syncthreads();

    // masked softmax over l per head (16-lane groups; t<128: hh=t>>4, ll=t&15)
    if (t < 128) {
        int hh = t >> 4, ll = t & 15;
        float s = scoresP[0][ll][hh] + scoresP[1][ll][hh]
                + scoresP[2][ll][hh] + scoresP[3][ll][hh] + sb[hh];
        bool valid = (amask[bp * 16 + ll] != 0) || (allzL && ll == 0);
        s = valid ? s : -1e30f;
        float mx = s;
        mx = fmaxf(mx, __shfl_xor(mx, 1)); mx = fmaxf(mx, __shfl_xor(mx, 2));
        mx = fmaxf(mx, __shfl_xor(mx, 4)); mx = fmaxf(mx, __shfl_xor(mx, 8));
        float e = __expf(s - mx);
        float sum = e;
        sum += __shfl_xor(sum, 1); sum += __shfl_xor(sum, 2);
        sum += __shfl_xor(sum, 4); sum += __shfl_xor(sum, 8);
        attnL[ll][hh] = e / sum;
    }
    __syncthreads();

    // mix: m[h][j] = sum_l attn[h][l] * tok[l][j]; thread owns 4 j's
    float macc[8][4];
    #pragma unroll
    for (int h = 0; h < 8; ++h)
        #pragma unroll
        for (int c = 0; c < 4; ++c) macc[h][c] = 0.f;
    #pragma unroll
    for (int ll = 0; ll < 16; ++ll) {
        uint2 tv = *(const uint2*)(&tokL[ll][t * 4]);
        float t0 = bflo(tv.x), t1 = bfhi(tv.x), t2 = bflo(tv.y), t3 = bfhi(tv.y);
        float4 a0 = *(const float4*)(&attnL[ll][0]);
        float4 a1 = *(const float4*)(&attnL[ll][4]);
        macc[0][0] = fmaf(a0.x, t0, macc[0][0]); macc[0][1] = fmaf(a0.x, t1, macc[0][1]);
        macc[0][2] = fmaf(a0.x, t2, macc[0][2]); macc[0][3] = fmaf(a0.x, t3, macc[0][3]);
        macc[1][0] = fmaf(a0.y, t0, macc[1][0]); macc[1][1] = fmaf(a0.y, t1, macc[1][1]);
        macc[1][2] = fmaf(a0.y, t2, macc[1][2]); macc[1][3] = fmaf(a0.y, t3, macc[1][3]);
        macc[2][0] = fmaf(a0.z, t0, macc[2][0]); macc[2][1] = fmaf(a0.z, t1, macc[2][1]);
        macc[2][2] = fmaf(a0.z, t2, macc[2][2]); macc[2][3] = fmaf(a0.z, t3, macc[2][3]);
        macc[3][0] = fmaf(a0.w, t0, macc[3][0]); macc[3][1] = fmaf(a0.w, t1, macc[3][1]);
        macc[3][2] = fmaf(a0.w, t2, macc[3][2]); macc[3][3] = fmaf(a0.w, t3, macc[3][3]);
        macc[4][0] = fmaf(a1.x, t0, macc[4][0]); macc[4][1] = fmaf(a1.x, t1, macc[4][1]);
        macc[4][2] = fmaf(a1.x, t2, macc[4][2]); macc[4][3] = fmaf(a1.x, t3, macc[4][3]);
        macc[5][0] = fmaf(a1.y, t0, macc[5][0]); macc[5][1] = fmaf(a1.y, t1, macc[5][1]);
        macc[5][2] = fmaf(a1.y, t2, macc[5][2]); macc[5][3] = fmaf(a1.y, t3, macc[5][3]);
        macc[6][0] = fmaf(a1.z, t0, macc[6][0]); macc[6][1] = fmaf(a1.z, t1, macc[6][1]);
        macc[6][2] = fmaf(a1.z, t2, macc[6][2]); macc[6][3] = fmaf(a1.z, t3, macc[6][3]);
        macc[7][0] = fmaf(a1.w, t0, macc[7][0]); macc[7][1] = fmaf(a1.w, t1, macc[7][1]);
        macc[7][2] = fmaf(a1.w, t2, macc[7][2]); macc[7][3] = fmaf(a1.w, t3, macc[7][3]);
    }
    #pragma unroll
    for (int h = 0; h < 8; ++h) {
        ushort4 o;
        o.x = f2bf(macc[h][0]); o.y = f2bf(macc[h][1]);
        o.z = f2bf(macc[h][2]); o.w = f2bf(macc[h][3]);
        *(ushort4*)(Mout + ((size_t)(h * 2048 + bp)) * 1024 + t * 4) = o;
    }
}

// ---------------------------------------------------------------------------
// 64x64x1024 NT bf16 MFMA mainloop — double-buffered, BK=128 staged as
// 4 x (64x32) sub-tiles (byte-identical per-subtile bank layout to the proven
// round-2 BK=64 form; only the subtile count per step changed 2->4).
// 8 steps instead of 16 halves the number of end-of-step barrier drains
// (each drain exposes full global->LDS latency).  LDS = 2 bufs x 16 KB x 2
// mats = 64 KB -> still exactly 2 blocks/CU (preserves the round-2 TLP win).
// K enumerated in the same ascending order -> bit-identical accumulation.
// A, B pre-offset to their 64-row ranges, both row-major stride 1024.
__device__ __forceinline__ void gemm64_mainloop(
    const unsigned short* __restrict__ A, const unsigned short* __restrict__ B,
    unsigned short* As, unsigned short* Bs, f32x4v acc[2][2]) {
    int t = threadIdx.x;
    int wave = t >> 6, lane = t & 63, lrow = lane & 15, quad = lane >> 4;
    int wm = wave & 1, wn = wave >> 1;
    size_t g0 = (size_t)(t >> 2) * 1024 + (t & 3) * 8;   // row t/4, col8 t%4
    #pragma unroll
    for (int mi = 0; mi < 2; ++mi)
        #pragma unroll
        for (int ni = 0; ni < 2; ++ni) acc[mi][ni] = (f32x4v){0.f, 0.f, 0.f, 0.f};

    auto stage = [&](int step, int buf) {
        int k0 = step * 128;
        unsigned short* as = As + buf * 8192;
        unsigned short* bs = Bs + buf * 8192;
        #pragma unroll
        for (int ks = 0; ks < 4; ++ks) {
            async16(A + g0 + k0 + ks * 32, as + ks * 2048 + t * 8);
            async16(B + g0 + k0 + ks * 32, bs + ks * 2048 + t * 8);
        }
    };

    stage(0, 0);
    __syncthreads();                       // drain prologue loads
    for (int s = 0; s < 8; ++s) {
        int cur = s & 1;
        if (s + 1 < 8) stage(s + 1, cur ^ 1);    // prefetch next K-tile
        const unsigned short* as = As + cur * 8192;
        const unsigned short* bs = Bs + cur * 8192;
        #pragma unroll
        for (int ks = 0; ks < 4; ++ks) {
            s16x8 af[2], bf[2];
            #pragma unroll
            for (int i = 0; i < 2; ++i) {
                af[i] = *(const s16x8*)(as + ks * 2048 + (wm * 32 + i * 16 + lrow) * 32 + quad * 8);
                bf[i] = *(const s16x8*)(bs + ks * 2048 + (wn * 32 + i * 16 + lrow) * 32 + quad * 8);
            }
            #pragma unroll
            for (int mi = 0; mi < 2; ++mi)
                #pragma unroll
                for (int ni = 0; ni < 2; ++ni)
                    acc[mi][ni] = __builtin_amdgcn_mfma_f32_16x16x32_bf16(af[mi], bf[ni], acc[mi][ni], 0, 0, 0);
        }
        __syncthreads();   // vmcnt(0): prefetch done; buffers safe to swap
    }
}

// Kernel 5: ctx[bp][n] = M_h[bp,:] . wv[n,:] + bv[n], h = n>>7.
// grid (32 mb, 16 nb): 64-row M block x 64-col n block (nb*64 spans one head).
__global__ __launch_bounds__(256) void k_gemm_ctx(
    const unsigned short* __restrict__ M, const unsigned short* __restrict__ wv,
    const float* __restrict__ ipb, unsigned short* __restrict__ ctx) {
    __shared__ unsigned short As[2 * 8192], Bs[2 * 8192];
    int mb = blockIdx.x, nb = blockIdx.y, h = nb >> 1;
    f32x4v acc[2][2];
    gemm64_mainloop(M + ((size_t)h * 2048 + mb * 64) * 1024,
                    wv + (size_t)nb * 64 * 1024, As, Bs, acc);
    int t = threadIdx.x, wave = t >> 6, lane = t & 63, lrow = lane & 15, quad = lane >> 4;
    int wm = wave & 1, wn = wave >> 1;
    #pragma unroll
    for (int ni = 0; ni < 2; ++ni) {
        int n_g = nb * 64 + wn * 32 + ni * 16 + lrow;
        float bias = ipb[2048 + n_g];
        #pragma unroll
        for (int mi = 0; mi < 2; ++mi) {
            #pragma unroll
            for (int r = 0; r < 4; ++r) {
                int m_g = mb * 64 + wm * 32 + mi * 16 + quad * 4 + r;
                ctx[(size_t)m_g * 1024 + n_g] = f2bf(acc[mi][ni][r] + bias);
            }
        }
    }
}

// Kernel 6: out[bp][n] = (ctx[bp,:] . out_w[n,:] + out_b[n]) * pv[bp]
// grid (32 mb, 16 nb); nb==0 blocks write the pv tail.
__global__ __launch_bounds__(256) void k_gemm_out(
    const unsigned short* __restrict__ ctx, const unsigned short* __restrict__ ow,
    const float* __restrict__ outb, const float* __restrict__ pv,
    float* __restrict__ out) {
    __shared__ unsigned short As[2 * 8192], Bs[2 * 8192];
    int mb = blockIdx.x, nb = blockIdx.y;
    f32x4v acc[2][2];
    gemm64_mainloop(ctx + (size_t)mb * 64 * 1024,
                    ow + (size_t)nb * 64 * 1024, As, Bs, acc);
    int t = threadIdx.x, wave = t >> 6, lane = t & 63, lrow = lane & 15, quad = lane >> 4;
    int wm = wave & 1, wn = wave >> 1;
    #pragma unroll
    for (int ni = 0; ni < 2; ++ni) {
        int n_g = nb * 64 + wn * 32 + ni * 16 + lrow;
        float bias = outb[n_g];
        #pragma unroll
        for (int mi = 0; mi < 2; ++mi) {
            #pragma unroll
            for (int r = 0; r < 4; ++r) {
                int m_g = mb * 64 + wm * 32 + mi * 16 + quad * 4 + r;
                out[(size_t)m_g * 1024 + n_g] = (acc[mi][ni][r] + bias) * pv[m_g];
            }
        }
    }
    if (nb == 0 && t < 64) out[OUT_LATENT + mb * 64 + t] = pv[mb * 64 + t];
}

// ---------------------------------------------------------------------------
extern "C" void kernel_launch(void* const* d_in, const int* in_sizes, int n_in,
                              void* d_out, int out_size, void* d_ws, size_t ws_size,
                              hipStream_t stream) {
    const int*   tok = (const int*)d_in[0];
    const int*   msk = (const int*)d_in[1];
    const float* emb = (const float*)d_in[2];
    const float* pq  = (const float*)d_in[3];
    const float* ipw = (const float*)d_in[4];
    const float* ipb = (const float*)d_in[5];
    const float* ow  = (const float*)d_in[6];
    const float* ob  = (const float*)d_in[7];
    float* out = (float*)d_out;
    char* ws = (char*)d_ws;

    float*          q_f   = (float*)(ws + 0);                       // 4 KB
    float*          sb_f  = (float*)(ws + 4096);                    // 32 B
    float*          pv_f  = (float*)(ws + 8192);                    // 8 KB
    unsigned short* qk_b  = (unsigned short*)(ws + 16384);          // 16 KB
    unsigned short* wv_b  = (unsigned short*)(ws + 32768);          // 2 MB
    unsigned short* ow_b  = (unsigned short*)(ws + 32768 + 2097152);            // 2 MB
    unsigned short* ctx_b = (unsigned short*)(ws + 32768 + 2 * 2097152);        // 4 MB
    unsigned short* M_b   = (unsigned short*)(ws + 32768 + 2 * 2097152 + 4194304); // 32 MB

    k_qvec <<<dim3(256),   dim3(256), 0, stream>>>(pq, ipw, ipb, q_f);
    k_qk   <<<dim3(8, 16), dim3(256), 0, stream>>>(q_f, ipw, ipb, qk_b, sb_f);
    k_attn_conv<<<dim3(4096), dim3(256), 0, stream>>>(
        tok, msk, emb, qk_b, sb_f, M_b, pv_f,
        ipw + (size_t)2048 * 1024, ow, wv_b, ow_b);
    k_gemm_ctx<<<dim3(32, 16), dim3(256), 0, stream>>>(M_b, wv_b, ipb, ctx_b);
    k_gemm_out<<<dim3(32, 16), dim3(256), 0, stream>>>(ctx_b, ow_b, ob, pv_f, out);
}